// Round 2
// baseline (39.550 us; speedup 1.0000x reference)
//
#include <hip/hip_runtime.h>
#include <hip/hip_bf16.h>

#define NB 16
#define NN 50
#define HW 256

// round(linspace(0,256,256))[i] == i + (i>=128); no round-half ties within f32 error.
__device__ __forceinline__ float gridc(int i) { return (float)(i + (i >= 128 ? 1 : 0)); }

__device__ __forceinline__ float wredmax(float v) {
#pragma unroll
  for (int o = 32; o > 0; o >>= 1) v = fmaxf(v, __shfl_xor(v, o));
  return v;
}
__device__ __forceinline__ float wredmin(float v) {
#pragma unroll
  for (int o = 32; o > 0; o >>= 1) v = fminf(v, __shfl_xor(v, o));
  return v;
}

// Pass A: per-(b,n) mask min/max via separability:
//   min/max over (i,j) of f1*ex[i]*ey[j] = f1 * (min/max ex) * (min/max ey)   (all > 0)
__global__ void k_minmax(const float* __restrict__ boxes, float2* __restrict__ mm) {
  int bn = blockIdx.x;  // b*NN + n
  float4 box = reinterpret_cast<const float4*>(boxes)[bn];
  float xc = box.x + floorf(box.z * 0.5f);
  float yc = box.y + floorf(box.w * 0.5f);
  int t = threadIdx.x;  // 0..255 == both row index and col index
  float g = gridc(t);
  float dx = g - xc, dy = g - yc;
  float ex = expf(-0.5f * (dx * dx) / (0.25f * box.z));
  float ey = expf(-0.5f * (dy * dy) / (0.25f * box.w));
  float exmx = wredmax(ex), exmn = wredmin(ex);
  float eymx = wredmax(ey), eymn = wredmin(ey);
  __shared__ float red[4][4];
  int wid = t >> 6;
  if ((t & 63) == 0) { red[wid][0] = exmx; red[wid][1] = exmn; red[wid][2] = eymx; red[wid][3] = eymn; }
  __syncthreads();
  if (t == 0) {
    float a = red[0][0], b2 = red[0][1], c = red[0][2], d = red[0][3];
#pragma unroll
    for (int k = 1; k < 4; ++k) {
      a = fmaxf(a, red[k][0]); b2 = fminf(b2, red[k][1]);
      c = fmaxf(c, red[k][2]); d = fminf(d, red[k][3]);
    }
    float det = 0.0625f * box.z * box.w;
    float f1 = 0.15915494309189535f / sqrtf(det);  // (2*pi)^-1 * det^-0.5
    mm[bn] = make_float2(f1 * b2 * d, f1 * a * c); // (min, max)
  }
}

// Pass B: per-batch reduce over the 50 (min,max) pairs -> (scale, mn*scale); also permuted labels.
__global__ void k_batch(const float2* __restrict__ mm, const float* __restrict__ labels,
                        float2* __restrict__ bp, float* __restrict__ out_labels) {
  int b = blockIdx.x;
  int t = threadIdx.x;  // 64 threads
  float mn = INFINITY, mx = -INFINITY;
  if (t < NN) { float2 v = mm[b * NN + t]; mn = v.x; mx = v.y; }
#pragma unroll
  for (int o = 32; o > 0; o >>= 1) {
    mn = fminf(mn, __shfl_xor(mn, o));
    mx = fmaxf(mx, __shfl_xor(mx, o));
  }
  if (t == 0) {
    float s = 50.0f / (mx - mn);        // SCALE_FACTOR / (mx - mn)
    bp[b] = make_float2(s, mn * s);
  }
  if (t < NN) {
    int src = (t < 25) ? 2 * t : 2 * (t - 25) + 1;  // channel-shuffle perm
    out_labels[b * NN + t] = labels[b * NN + src];
  }
}

// Pass C: write masks (f32). One block = one (b, dest-channel k, 64-row tile). 256 threads.
// Each row (256 f32 = 1 KB) is written by one 64-lane wave as float4 stores.
__global__ void k_masks(const float* __restrict__ boxes, const float2* __restrict__ bp,
                        float* __restrict__ out) {
  int blk = blockIdx.x;
  int tile = blk & 3;        // 0..3 -> rows tile*64..tile*64+63
  int bk = blk >> 2;         // b*NN + k (dest channel)
  int b = bk / NN;
  int k = bk - b * NN;
  int n = (k < 25) ? 2 * k : 2 * (k - 25) + 1;  // source channel
  float4 box = reinterpret_cast<const float4*>(boxes)[b * NN + n];
  float xc = box.x + floorf(box.z * 0.5f);
  float yc = box.y + floorf(box.w * 0.5f);
  float2 p = bp[b];
  float s = p.x, mns = p.y;
  float det = 0.0625f * box.z * box.w;
  float A = (0.15915494309189535f / sqrtf(det)) * s;  // folded factor1*scale

  __shared__ float eyL[HW];
  __shared__ float exL[64];
  int t = threadIdx.x;
  {
    float g = gridc(t);
    float d = g - yc;
    eyL[t] = expf(-0.5f * (d * d) / (0.25f * box.w));
  }
  int row0 = tile * 64;
  if (t < 64) {
    float g = gridc(row0 + t);
    float d = g - xc;
    exL[t] = A * expf(-0.5f * (d * d) / (0.25f * box.z));
  }
  __syncthreads();

  int lane_col = (t & 63) * 4;  // 64 lanes span one row, 4 cols each
  int rsub = t >> 6;            // 0..3
  float eyr[4];
#pragma unroll
  for (int c = 0; c < 4; ++c) eyr[c] = eyL[lane_col + c];  // one-time LDS read, reused 16x

  float* base = out + (size_t)bk * (HW * HW) + (size_t)row0 * HW;
#pragma unroll
  for (int it = 0; it < 16; ++it) {
    int r = rsub + it * 4;      // 0..63 within tile
    float coef = exL[r];
    float4 v;
    v.x = fmaf(coef, eyr[0], -mns);   // mask*s - mn*s
    v.y = fmaf(coef, eyr[1], -mns);
    v.z = fmaf(coef, eyr[2], -mns);
    v.w = fmaf(coef, eyr[3], -mns);
    *reinterpret_cast<float4*>(base + r * HW + lane_col) = v;
  }
}

extern "C" void kernel_launch(void* const* d_in, const int* in_sizes, int n_in,
                              void* d_out, int out_size, void* d_ws, size_t ws_size,
                              hipStream_t stream) {
  const float* boxes = (const float*)d_in[0];
  const float* labels = (const float*)d_in[1];
  float* out = (float*)d_out;

  float2* mm = (float2*)d_ws;                                     // [NB*NN] (min,max)
  float2* bp = (float2*)((char*)d_ws + NB * NN * sizeof(float2)); // [NB] (scale, mn*scale)

  k_minmax<<<NB * NN, 256, 0, stream>>>(boxes, mm);
  k_batch<<<NB, 64, 0, stream>>>(mm, labels, bp, out + (size_t)NB * NN * HW * HW);
  k_masks<<<NB * NN * 4, 256, 0, stream>>>(boxes, bp, out);
}

// Round 3
// 33.046 us; speedup vs baseline: 1.1968x; 1.1968x over previous
//
#include <hip/hip_runtime.h>
#include <hip/hip_bf16.h>

#define NB 16
#define NN 50
#define HW 256

// round(linspace(0,256,256))[i] == i + (i>=128); no round-half ties within f32 error.
// Grid value set is {0..127} U {129..256}  (128 is missing).
__device__ __forceinline__ float gridc(int i) { return (float)(i + (i >= 128 ? 1 : 0)); }

// Nearest grid value to continuous coordinate c (c in [5,230] for this problem).
__device__ __forceinline__ float nearest_grid(float c) {
  float r = rintf(c);
  if (r == 128.0f) r = (c < 128.0f) ? 127.0f : 129.0f;  // 128 not in grid; tie -> equal dist
  return r;
}

// Single fused kernel. One block = one (b, dest-channel k, 64-row tile); 3200 blocks x 256.
// Phase 1: threads 0..49 compute their batch's per-channel mask min/max ANALYTICALLY
//   (separable gaussian: extreme over grid = product of 1-D extremes; max at nearest
//    grid point, min at farthest endpoint), wave-0 reduces over the 50 channels.
// Phase 2: separable row/col exp tables in LDS, float4 coalesced stores.
__global__ void k_fused(const float* __restrict__ boxes, const float* __restrict__ labels,
                        float* __restrict__ out) {
  int blk = blockIdx.x;
  int tile = blk & 3;        // 0..3 -> rows tile*64 .. tile*64+63
  int bk = blk >> 2;         // b*NN + k (dest channel)
  int b = bk / NN;
  int k = bk - b * NN;
  int n = (k < 25) ? 2 * k : 2 * (k - 25) + 1;  // channel-shuffle source

  const float4* boxes4 = reinterpret_cast<const float4*>(boxes);
  int t = threadIdx.x;

  // ---- Phase 1: per-batch normalization constants (redundant per block; VALU is idle) ----
  __shared__ float sS, sMns;
  float mn = INFINITY, mx = -INFINITY;
  if (t < NN) {
    float4 bx = boxes4[b * NN + t];
    float xc = bx.x + floorf(bx.z * 0.5f);
    float yc = bx.y + floorf(bx.w * 0.5f);
    float gnx = nearest_grid(xc), gfx = (xc > 128.0f) ? 0.0f : 256.0f;
    float gny = nearest_grid(yc), gfy = (yc > 128.0f) ? 0.0f : 256.0f;
    float dnx = gnx - xc, dfx = gfx - xc, dny = gny - yc, dfy = gfy - yc;
    float exmx = expf(-0.5f * (dnx * dnx) / (0.25f * bx.z));
    float exmn = expf(-0.5f * (dfx * dfx) / (0.25f * bx.z));
    float eymx = expf(-0.5f * (dny * dny) / (0.25f * bx.w));
    float eymn = expf(-0.5f * (dfy * dfy) / (0.25f * bx.w));
    float det = 0.0625f * bx.z * bx.w;
    float f1 = 0.15915494309189535f / sqrtf(det);  // (2*pi)^-1 * det^-0.5
    mn = f1 * exmn * eymn;
    mx = f1 * exmx * eymx;
  }
  if (t < 64) {  // wave 0 reduces channels 0..49 (50..63 hold identities)
#pragma unroll
    for (int o = 32; o > 0; o >>= 1) {
      mn = fminf(mn, __shfl_xor(mn, o));
      mx = fmaxf(mx, __shfl_xor(mx, o));
    }
    if (t == 0) {
      float s = 50.0f / (mx - mn);  // SCALE_FACTOR / (mx - mn)
      sS = s;
      sMns = mn * s;
    }
  }

  // ---- labels: 16 blocks (k==0, tile==0) write the 50 permuted labels of their batch ----
  if (k == 0 && tile == 0 && t < NN) {
    int src = (t < 25) ? 2 * t : 2 * (t - 25) + 1;
    out[(size_t)NB * NN * HW * HW + b * NN + t] = labels[b * NN + src];
  }

  // ---- Phase 2: separable exp tables for THIS channel ----
  float4 box = boxes4[b * NN + n];
  float xc = box.x + floorf(box.z * 0.5f);
  float yc = box.y + floorf(box.w * 0.5f);
  float det = 0.0625f * box.z * box.w;
  float f1 = 0.15915494309189535f / sqrtf(det);

  __shared__ float eyL[HW];
  __shared__ float exL[64];
  {
    float g = gridc(t);
    float d = g - yc;
    eyL[t] = expf(-0.5f * (d * d) / (0.25f * box.w));
  }
  int row0 = tile * 64;
  if (t < 64) {
    float g = gridc(row0 + t);
    float d = g - xc;
    exL[t] = expf(-0.5f * (d * d) / (0.25f * box.z));
  }
  __syncthreads();

  float A = f1 * sS;     // folded factor1 * scale
  float mns = sMns;

  int lane_col = (t & 63) * 4;  // one 64-lane wave spans a 1 KB row, float4 each
  int rsub = t >> 6;            // 0..3
  float eyr[4];
#pragma unroll
  for (int c = 0; c < 4; ++c) eyr[c] = eyL[lane_col + c];

  float* base = out + (size_t)bk * (HW * HW) + (size_t)row0 * HW;
#pragma unroll
  for (int it = 0; it < 16; ++it) {
    int r = rsub + it * 4;      // 0..63 within tile
    float coef = A * exL[r];
    float4 v;
    v.x = fmaf(coef, eyr[0], -mns);   // mask*s - mn*s
    v.y = fmaf(coef, eyr[1], -mns);
    v.z = fmaf(coef, eyr[2], -mns);
    v.w = fmaf(coef, eyr[3], -mns);
    *reinterpret_cast<float4*>(base + r * HW + lane_col) = v;
  }
}

extern "C" void kernel_launch(void* const* d_in, const int* in_sizes, int n_in,
                              void* d_out, int out_size, void* d_ws, size_t ws_size,
                              hipStream_t stream) {
  const float* boxes = (const float*)d_in[0];
  const float* labels = (const float*)d_in[1];
  float* out = (float*)d_out;
  k_fused<<<NB * NN * 4, 256, 0, stream>>>(boxes, labels, out);
}